// Round 3
// baseline (388.362 us; speedup 1.0000x reference)
//
#include <hip/hip_runtime.h>

typedef float f32x4 __attribute__((ext_vector_type(4)));
typedef short s16x4 __attribute__((ext_vector_type(4)));
typedef short s16x8 __attribute__((ext_vector_type(8)));

__device__ __forceinline__ short f2bf(float f) {
    union { float f; unsigned u; } c; c.f = f;
    return (short)((c.u + 0x7FFFu + ((c.u >> 16) & 1u)) >> 16);
}
__device__ __forceinline__ unsigned pack2(float lo, float hi) {
    return (unsigned)(unsigned short)f2bf(lo) |
           ((unsigned)(unsigned short)f2bf(hi) << 16);
}

// 16B-granular XOR swizzle on a short index (byte ^= ((row&7)<<4)).
__device__ __forceinline__ int swz128(int row, int col) {
    return row * 128 + (col ^ ((row & 7) << 3));
}
__device__ __forceinline__ int swz64(int row, int col) {
    return row * 64 + (col ^ ((row & 7) << 3));
}

// ---- prep: transpose 5 fp32 [k][n] weights into bf16 [n][k] in workspace ----
__global__ __launch_bounds__(256) void k_prep(
    const float* __restrict__ Wq, const float* __restrict__ Wk,
    const float* __restrict__ Wv, const float* __restrict__ Wot,
    const float* __restrict__ Wtg, short* __restrict__ Wt) {
    const float* srcs[5] = {Wq, Wk, Wv, Wot, Wtg};
    const float* W = srcs[blockIdx.x];
    short* dst = Wt + blockIdx.x * 16384;
    const int t = threadIdx.x;
#pragma unroll 4
    for (int i = 0; i < 64; ++i) {
        int idx = i * 256 + t;
        int k = idx >> 7, n = idx & 127;
        dst[n * 128 + k] = f2bf(W[idx]);
    }
}

// B-fragment from pre-transposed bf16 weight: Wt[n][k], n=ni*16+m, k=kk*32+quad*8
__device__ __forceinline__ s16x8 wfrag(const short* __restrict__ Wt,
                                       int ni, int kk, int m, int quad) {
    return *(const s16x8*)(Wt + (ni * 16 + m) * 128 + kk * 32 + quad * 8);
}

// LDS = 16K (B2) + 16K (B3) + 8K (BS) = 40960 B exactly -> 4 blocks/CU.
__global__ __launch_bounds__(256, 4) void k_main(
    const float* __restrict__ XQ, const float* __restrict__ XK,
    const float* __restrict__ Tgt, const short* __restrict__ Wt,
    const float* __restrict__ bq, const float* __restrict__ bk,
    const float* __restrict__ bv, const float* __restrict__ bot,
    const float* __restrict__ btg,
    const float* __restrict__ g_time, const float* __restrict__ b_time,
    const float* __restrict__ g_tgt, const float* __restrict__ b_tgt,
    float* __restrict__ out0, float* __restrict__ out1, float* __restrict__ out2) {
    const int bn = blockIdx.x;
    const int t = threadIdx.x;
    const int w = t >> 6, lane = t & 63, m = lane & 15, quad = lane >> 4;
    const int r0 = w * 16;  // this wave's 16-row band

    __shared__ short B2[64 * 128];    // XK stage -> k -> ct band
    __shared__ short B3[64 * 128];    // XQ stage -> q band -> v^T[128][64] -> tv band
    __shared__ short BS[4][16 * 64];  // per-wave S band (wave-private)

    const size_t base = (size_t)bn * 8192;
    const short* Wqt = Wt;
    const short* Wkt = Wt + 16384;
    const short* Wvt = Wt + 32768;
    const short* Wot_t = Wt + 49152;
    const short* Wtg_t = Wt + 65536;
    short* myS = BS[w];

    // ---------- stage XQ -> B3 (coalesced f32x4, bf16, swizzled) ------------
    {
        const float* sq = XQ + base;
#pragma unroll
        for (int it = 0; it < 8; ++it) {
            int e = t + it * 256;
            int row = e >> 5, c4 = (e & 31) * 4;
            f32x4 x = *(const f32x4*)(sq + e * 4);
            s16x4 p;
#pragma unroll
            for (int r = 0; r < 4; ++r) p[r] = f2bf(x[r]);
            *(s16x4*)(B3 + swz128(row, c4)) = p;
        }
    }
    __syncthreads();  // A: XQ staged

    // ---------- region 1: XK loads in flight under q-projection -------------
    s16x8 qf[8];
    {
        const float* sk = XK + base;
        f32x4 xk[8];
#pragma unroll
        for (int it = 0; it < 8; ++it)
            xk[it] = *(const f32x4*)(sk + (t + it * 256) * 4);  // issued early

        // q = XQ@Wq + bq (A-frags from own B3 band)
        s16x8 a[4];
#pragma unroll
        for (int kk = 0; kk < 4; ++kk)
            a[kk] = *(const s16x8*)(B3 + swz128(r0 + m, kk * 32 + quad * 8));
        f32x4 accq[8];
#pragma unroll
        for (int ni = 0; ni < 8; ++ni) {
            accq[ni] = (f32x4){0.f, 0.f, 0.f, 0.f};
#pragma unroll
            for (int kk = 0; kk < 4; ++kk)
                accq[ni] = __builtin_amdgcn_mfma_f32_16x16x32_bf16(
                    a[kk], wfrag(Wqt, ni, kk, m, quad), accq[ni], 0, 0, 0);
        }
        // scatter q into own B3 band (in-place over staged XQ; wave-private)
#pragma unroll
        for (int ni = 0; ni < 8; ++ni) {
            const float bb = bq[ni * 16 + m];
#pragma unroll
            for (int r = 0; r < 4; ++r)
                B3[swz128(r0 + quad * 4 + r, ni * 16 + m)] = f2bf(accq[ni][r] + bb);
        }
#pragma unroll
        for (int h = 0; h < 8; ++h) {
            qf[h] = (s16x8){0, 0, 0, 0, 0, 0, 0, 0};
            if (quad < 2)
                qf[h] = *(const s16x8*)(B3 + swz128(r0 + m, h * 16 + quad * 8));
        }
        // write staged XK -> B2
#pragma unroll
        for (int it = 0; it < 8; ++it) {
            int e = t + it * 256;
            int row = e >> 5, c4 = (e & 31) * 4;
            s16x4 p;
#pragma unroll
            for (int r = 0; r < 4; ++r) p[r] = f2bf(xk[it][r]);
            *(s16x4*)(B2 + swz128(row, c4)) = p;
        }
    }
    __syncthreads();  // B: XK staged everywhere; all qf readbacks done

    // ---------- k = XK@Wk + bk -> B2 (own band), v^T -> B3 [128][64] --------
    {
        s16x8 a[4];
#pragma unroll
        for (int kk = 0; kk < 4; ++kk)
            a[kk] = *(const s16x8*)(B2 + swz128(r0 + m, kk * 32 + quad * 8));
        f32x4 acck[8], accv[8];
#pragma unroll
        for (int ni = 0; ni < 8; ++ni) {
            acck[ni] = (f32x4){0.f, 0.f, 0.f, 0.f};
            accv[ni] = (f32x4){0.f, 0.f, 0.f, 0.f};
#pragma unroll
            for (int kk = 0; kk < 4; ++kk) {
                acck[ni] = __builtin_amdgcn_mfma_f32_16x16x32_bf16(
                    a[kk], wfrag(Wkt, ni, kk, m, quad), acck[ni], 0, 0, 0);
                accv[ni] = __builtin_amdgcn_mfma_f32_16x16x32_bf16(
                    a[kk], wfrag(Wvt, ni, kk, m, quad), accv[ni], 0, 0, 0);
            }
        }
#pragma unroll
        for (int ni = 0; ni < 8; ++ni) {
            const float bbk = bk[ni * 16 + m];
            const float bbv = bv[ni * 16 + m];
#pragma unroll
            for (int r = 0; r < 4; ++r) {
                B2[swz128(r0 + quad * 4 + r, ni * 16 + m)] = f2bf(acck[ni][r] + bbk);
                B3[swz64(ni * 16 + m, r0 + quad * 4 + r)] = f2bf(accv[ni][r] + bbv);
            }
        }
    }
    __syncthreads();  // C: k, v^T visible; head loop is barrier-free

    // ---------- per-head: S = q k^T/4 ; tv += S v ; ct += S tk --------------
    unsigned pv[8][2], pt[8][2];
    const s16x8 zfrag = (s16x8){0, 0, 0, 0, 0, 0, 0, 0};
    float* o0 = out0 + (size_t)bn * 32768;
#pragma unroll
    for (int h = 0; h < 8; ++h) {
        // Tgt^T B-frags straight from global (64B-segment coalesced, L2-hot)
        const float* tg = Tgt + base + h * 16 + m;
        float tgv[16];
#pragma unroll
        for (int j = 0; j < 8; ++j) {
            tgv[j]     = tg[(quad * 8 + j) * 128];
            tgv[8 + j] = tg[(32 + quad * 8 + j) * 128];
        }

        const s16x8 aq = qf[h];
#pragma unroll
        for (int nj = 0; nj < 4; ++nj) {
            s16x8 bk_ = zfrag;
            if (quad < 2)
                bk_ = *(const s16x8*)(B2 + swz128(nj * 16 + m, h * 16 + quad * 8));
            f32x4 s = __builtin_amdgcn_mfma_f32_16x16x32_bf16(
                aq, bk_, (f32x4){0.f, 0.f, 0.f, 0.f}, 0, 0, 0);
#pragma unroll
            for (int r = 0; r < 4; ++r) {
                const int row = r0 + quad * 4 + r;
                const float sval = s[r] * 0.25f;
                o0[h * 4096 + row * 64 + nj * 16 + m] = sval;
                myS[swz64(quad * 4 + r, nj * 16 + m)] = f2bf(sval);
            }
        }
        s16x8 bt0, bt1;
#pragma unroll
        for (int j = 0; j < 8; ++j) { bt0[j] = f2bf(tgv[j]); bt1[j] = f2bf(tgv[8 + j]); }

        f32x4 av = (f32x4){0.f, 0.f, 0.f, 0.f};
        f32x4 at = (f32x4){0.f, 0.f, 0.f, 0.f};
        {
            s16x8 sa0 = *(const s16x8*)(myS + swz64(m, quad * 8));
            s16x8 bv0 = *(const s16x8*)(B3 + swz64(h * 16 + m, quad * 8));
            av = __builtin_amdgcn_mfma_f32_16x16x32_bf16(sa0, bv0, av, 0, 0, 0);
            at = __builtin_amdgcn_mfma_f32_16x16x32_bf16(sa0, bt0, at, 0, 0, 0);
            s16x8 sa1 = *(const s16x8*)(myS + swz64(m, 32 + quad * 8));
            s16x8 bv1 = *(const s16x8*)(B3 + swz64(h * 16 + m, 32 + quad * 8));
            av = __builtin_amdgcn_mfma_f32_16x16x32_bf16(sa1, bv1, av, 0, 0, 0);
            at = __builtin_amdgcn_mfma_f32_16x16x32_bf16(sa1, bt1, at, 0, 0, 0);
        }
        // pack accumulators to bf16 now (they only ever get f2bf'd anyway)
        pv[h][0] = pack2(av[0], av[1]); pv[h][1] = pack2(av[2], av[3]);
        pt[h][0] = pack2(at[0], at[1]); pt[h][1] = pack2(at[2], at[3]);
    }
    __syncthreads();  // D: all cross-wave B2/B3 reads done before band reuse

    // ---------- tv -> B3 own band, ct -> B2 own band (wave-private) ---------
#pragma unroll
    for (int h = 0; h < 8; ++h) {
#pragma unroll
        for (int j = 0; j < 2; ++j) {
            const int ra = r0 + quad * 4 + 2 * j, rb = ra + 1;
            B3[swz128(ra, h * 16 + m)] = (short)(pv[h][j] & 0xffff);
            B3[swz128(rb, h * 16 + m)] = (short)(pv[h][j] >> 16);
            B2[swz128(ra, h * 16 + m)] = (short)(pt[h][j] & 0xffff);
            B2[swz128(rb, h * 16 + m)] = (short)(pt[h][j] >> 16);
        }
    }

    // ---------- output projections + LayerNorm ------------------------------
#pragma unroll
    for (int br = 0; br < 2; ++br) {
        const short* sA = br == 0 ? B3 : B2;
        const short* Wp = br == 0 ? Wot_t : Wtg_t;
        const float* bias = br == 0 ? bot : btg;
        const float* gam = br == 0 ? g_time : g_tgt;
        const float* bet = br == 0 ? b_time : b_tgt;
        float* outp = (br == 0 ? out1 : out2) + base;
        const float* resid = br == 0 ? XQ + base : nullptr;

        s16x8 a[4];
#pragma unroll
        for (int kk = 0; kk < 4; ++kk)
            a[kk] = *(const s16x8*)(sA + swz128(r0 + m, kk * 32 + quad * 8));
        f32x4 acc[8];
#pragma unroll
        for (int ni = 0; ni < 8; ++ni) {
            acc[ni] = (f32x4){0.f, 0.f, 0.f, 0.f};
#pragma unroll
            for (int kk = 0; kk < 4; ++kk)
                acc[ni] = __builtin_amdgcn_mfma_f32_16x16x32_bf16(
                    a[kk], wfrag(Wp, ni, kk, m, quad), acc[ni], 0, 0, 0);
        }
        float y[8][4];
        float s1[4] = {0.f, 0.f, 0.f, 0.f}, s2[4] = {0.f, 0.f, 0.f, 0.f};
#pragma unroll
        for (int ni = 0; ni < 8; ++ni) {
            const int col = ni * 16 + m;
            const float bb = bias[col];
#pragma unroll
            for (int r = 0; r < 4; ++r) {
                const int row = r0 + quad * 4 + r;
                float v = acc[ni][r] + bb;
                if (resid) v += resid[row * 128 + col];
                y[ni][r] = v;
                s1[r] += v;
                s2[r] += v * v;
            }
        }
#pragma unroll
        for (int mask = 1; mask < 16; mask <<= 1) {
#pragma unroll
            for (int r = 0; r < 4; ++r) {
                s1[r] += __shfl_xor(s1[r], mask, 64);
                s2[r] += __shfl_xor(s2[r], mask, 64);
            }
        }
        float mu[4], rstd[4];
#pragma unroll
        for (int r = 0; r < 4; ++r) {
            mu[r] = s1[r] * (1.0f / 128.0f);
            float var = s2[r] * (1.0f / 128.0f) - mu[r] * mu[r];
            rstd[r] = rsqrtf(var + 1e-5f);
        }
#pragma unroll
        for (int ni = 0; ni < 8; ++ni) {
            const int col = ni * 16 + m;
            const float g = gam[col], bb = bet[col];
#pragma unroll
            for (int r = 0; r < 4; ++r) {
                const int row = r0 + quad * 4 + r;
                outp[row * 128 + col] = (y[ni][r] - mu[r]) * rstd[r] * g + bb;
            }
        }
    }
}

extern "C" void kernel_launch(void* const* d_in, const int* in_sizes, int n_in,
                              void* d_out, int out_size, void* d_ws, size_t ws_size,
                              hipStream_t stream) {
    const float* XQ  = (const float*)d_in[0];
    const float* XK  = (const float*)d_in[1];
    const float* Tgt = (const float*)d_in[2];
    const float* Wq  = (const float*)d_in[3];
    const float* bq  = (const float*)d_in[4];
    const float* Wk  = (const float*)d_in[5];
    const float* bk  = (const float*)d_in[6];
    const float* Wv  = (const float*)d_in[7];
    const float* bv  = (const float*)d_in[8];
    const float* Wot = (const float*)d_in[9];
    const float* bot = (const float*)d_in[10];
    const float* Wtg = (const float*)d_in[11];
    const float* btg = (const float*)d_in[12];
    const float* g_time = (const float*)d_in[13];
    const float* b_time = (const float*)d_in[14];
    const float* g_tgt  = (const float*)d_in[15];
    const float* b_tgt  = (const float*)d_in[16];

    const int BN = in_sizes[0] / 8192;  // B*N

    short* Wt = (short*)d_ws;  // 5 * 128 * 128 bf16 = 160 KB

    float* out0 = (float*)d_out;
    float* out1 = out0 + (size_t)BN * 32768;
    float* out2 = out1 + (size_t)BN * 8192;

    k_prep<<<5, 256, 0, stream>>>(Wq, Wk, Wv, Wot, Wtg, Wt);
    k_main<<<BN, 256, 0, stream>>>(XQ, XK, Tgt, Wt, bq, bk, bv, bot, btg,
                                   g_time, b_time, g_tgt, b_tgt,
                                   out0, out1, out2);
}

// Round 4
// 380.094 us; speedup vs baseline: 1.0218x; 1.0218x over previous
//
#include <hip/hip_runtime.h>

typedef float f32x4 __attribute__((ext_vector_type(4)));
typedef short s16x4 __attribute__((ext_vector_type(4)));
typedef short s16x8 __attribute__((ext_vector_type(8)));

__device__ __forceinline__ short f2bf(float f) {
    union { float f; unsigned u; } c; c.f = f;
    return (short)((c.u + 0x7FFFu + ((c.u >> 16) & 1u)) >> 16);
}
__device__ __forceinline__ unsigned pack2(float lo, float hi) {
    return (unsigned)(unsigned short)f2bf(lo) |
           ((unsigned)(unsigned short)f2bf(hi) << 16);
}

// 16B-granular XOR swizzle on a short index (byte ^= ((row&7)<<4)).
__device__ __forceinline__ int swz128(int row, int col) {
    return row * 128 + (col ^ ((row & 7) << 3));
}
__device__ __forceinline__ int swz64(int row, int col) {
    return row * 64 + (col ^ ((row & 7) << 3));
}

// ---- prep: transpose 5 fp32 [k][n] weights into bf16 [n][k] in workspace ----
__global__ __launch_bounds__(256) void k_prep(
    const float* __restrict__ Wq, const float* __restrict__ Wk,
    const float* __restrict__ Wv, const float* __restrict__ Wot,
    const float* __restrict__ Wtg, short* __restrict__ Wt) {
    const float* srcs[5] = {Wq, Wk, Wv, Wot, Wtg};
    const float* W = srcs[blockIdx.x];
    short* dst = Wt + blockIdx.x * 16384;
    const int t = threadIdx.x;
#pragma unroll 4
    for (int i = 0; i < 64; ++i) {
        int idx = i * 256 + t;
        int k = idx >> 7, n = idx & 127;
        dst[n * 128 + k] = f2bf(W[idx]);
    }
}

// B-fragment from pre-transposed bf16 weight: Wt[n][k], n=ni*16+m, k=kk*32+quad*8
__device__ __forceinline__ s16x8 wfrag(const short* __restrict__ Wt,
                                       int ni, int kk, int m, int quad) {
    return *(const s16x8*)(Wt + (ni * 16 + m) * 128 + kk * 32 + quad * 8);
}

// LDS = 16K (B2) + 16K (B3) + 8K (BS) = 40960 B.
// (256,3): VGPR cap ~170 -> NO spills (R3's (256,4) forced 64 VGPR + 103 MB
// scratch traffic). 3 blocks/CU, VGPR-capped.
__global__ __launch_bounds__(256, 3) void k_main(
    const float* __restrict__ XQ, const float* __restrict__ XK,
    const float* __restrict__ Tgt, const short* __restrict__ Wt,
    const float* __restrict__ bq, const float* __restrict__ bk,
    const float* __restrict__ bv, const float* __restrict__ bot,
    const float* __restrict__ btg,
    const float* __restrict__ g_time, const float* __restrict__ b_time,
    const float* __restrict__ g_tgt, const float* __restrict__ b_tgt,
    float* __restrict__ out0, float* __restrict__ out1, float* __restrict__ out2) {
    const int bn = blockIdx.x;
    const int t = threadIdx.x;
    const int w = t >> 6, lane = t & 63, m = lane & 15, quad = lane >> 4;
    const int r0 = w * 16;  // this wave's 16-row band

    __shared__ short B2[64 * 128];    // XK stage -> k -> ct band
    __shared__ short B3[64 * 128];    // XQ stage -> q band -> v^T[128][64] -> tv band
    __shared__ short BS[4][16 * 64];  // per-wave S band (wave-private)

    const size_t base = (size_t)bn * 8192;
    const short* Wqt = Wt;
    const short* Wkt = Wt + 16384;
    const short* Wvt = Wt + 32768;
    const short* Wot_t = Wt + 49152;
    const short* Wtg_t = Wt + 65536;
    short* myS = BS[w];

    // ---------- stage XQ -> B3 (coalesced f32x4, bf16, swizzled) ------------
    {
        const float* sq = XQ + base;
#pragma unroll
        for (int it = 0; it < 8; ++it) {
            int e = t + it * 256;
            int row = e >> 5, c4 = (e & 31) * 4;
            f32x4 x = *(const f32x4*)(sq + e * 4);
            s16x4 p;
#pragma unroll
            for (int r = 0; r < 4; ++r) p[r] = f2bf(x[r]);
            *(s16x4*)(B3 + swz128(row, c4)) = p;
        }
    }
    __syncthreads();  // A: XQ staged

    // ---------- region 1: XK loads in flight under q-projection -------------
    s16x8 qf[8];
    {
        const float* sk = XK + base;
        f32x4 xk[8];
#pragma unroll
        for (int it = 0; it < 8; ++it)
            xk[it] = *(const f32x4*)(sk + (t + it * 256) * 4);  // issued early

        // q = XQ@Wq + bq (A-frags from own B3 band)
        s16x8 a[4];
#pragma unroll
        for (int kk = 0; kk < 4; ++kk)
            a[kk] = *(const s16x8*)(B3 + swz128(r0 + m, kk * 32 + quad * 8));
        f32x4 accq[8];
#pragma unroll
        for (int ni = 0; ni < 8; ++ni) {
            accq[ni] = (f32x4){0.f, 0.f, 0.f, 0.f};
#pragma unroll
            for (int kk = 0; kk < 4; ++kk)
                accq[ni] = __builtin_amdgcn_mfma_f32_16x16x32_bf16(
                    a[kk], wfrag(Wqt, ni, kk, m, quad), accq[ni], 0, 0, 0);
        }
        // scatter q into own B3 band (in-place over staged XQ; wave-private)
#pragma unroll
        for (int ni = 0; ni < 8; ++ni) {
            const float bb = bq[ni * 16 + m];
#pragma unroll
            for (int r = 0; r < 4; ++r)
                B3[swz128(r0 + quad * 4 + r, ni * 16 + m)] = f2bf(accq[ni][r] + bb);
        }
#pragma unroll
        for (int h = 0; h < 8; ++h) {
            qf[h] = (s16x8){0, 0, 0, 0, 0, 0, 0, 0};
            if (quad < 2)
                qf[h] = *(const s16x8*)(B3 + swz128(r0 + m, h * 16 + quad * 8));
        }
        // write staged XK -> B2
#pragma unroll
        for (int it = 0; it < 8; ++it) {
            int e = t + it * 256;
            int row = e >> 5, c4 = (e & 31) * 4;
            s16x4 p;
#pragma unroll
            for (int r = 0; r < 4; ++r) p[r] = f2bf(xk[it][r]);
            *(s16x4*)(B2 + swz128(row, c4)) = p;
        }
    }
    __syncthreads();  // B: XK staged everywhere; all qf readbacks done

    // ---------- k = XK@Wk + bk -> B2 (own band), v^T -> B3 [128][64] --------
    {
        s16x8 a[4];
#pragma unroll
        for (int kk = 0; kk < 4; ++kk)
            a[kk] = *(const s16x8*)(B2 + swz128(r0 + m, kk * 32 + quad * 8));
        f32x4 acck[8], accv[8];
#pragma unroll
        for (int ni = 0; ni < 8; ++ni) {
            acck[ni] = (f32x4){0.f, 0.f, 0.f, 0.f};
            accv[ni] = (f32x4){0.f, 0.f, 0.f, 0.f};
#pragma unroll
            for (int kk = 0; kk < 4; ++kk) {
                acck[ni] = __builtin_amdgcn_mfma_f32_16x16x32_bf16(
                    a[kk], wfrag(Wkt, ni, kk, m, quad), acck[ni], 0, 0, 0);
                accv[ni] = __builtin_amdgcn_mfma_f32_16x16x32_bf16(
                    a[kk], wfrag(Wvt, ni, kk, m, quad), accv[ni], 0, 0, 0);
            }
        }
#pragma unroll
        for (int ni = 0; ni < 8; ++ni) {
            const float bbk = bk[ni * 16 + m];
            const float bbv = bv[ni * 16 + m];
#pragma unroll
            for (int r = 0; r < 4; ++r) {
                B2[swz128(r0 + quad * 4 + r, ni * 16 + m)] = f2bf(acck[ni][r] + bbk);
                B3[swz64(ni * 16 + m, r0 + quad * 4 + r)] = f2bf(accv[ni][r] + bbv);
            }
        }
    }
    __syncthreads();  // C: k, v^T visible; head loop is barrier-free

    // ---------- per-head: S = q k^T/4 ; tv += S v ; ct += S tk --------------
    // Tgt B-frags double-buffered: head h+1's loads issue at top of head h,
    // consumed one iteration later (latency hidden under S/PV MFMAs).
    unsigned pv[8][2], pt[8][2];
    const s16x8 zfrag = (s16x8){0, 0, 0, 0, 0, 0, 0, 0};
    float* o0 = out0 + (size_t)bn * 32768;
    const float* tg = Tgt + base + m;
    float tgA[16], tgB[16];
#pragma unroll
    for (int j = 0; j < 8; ++j) {
        tgA[j]     = tg[(quad * 8 + j) * 128];
        tgA[8 + j] = tg[(32 + quad * 8 + j) * 128];
    }
#pragma unroll
    for (int h = 0; h < 8; ++h) {
        const float* cur = (h & 1) ? tgB : tgA;  // h literal under unroll
        float* nxt = (h & 1) ? tgA : tgB;
        if (h < 7) {
            const float* tgn = tg + (h + 1) * 16;
#pragma unroll
            for (int j = 0; j < 8; ++j) {
                nxt[j]     = tgn[(quad * 8 + j) * 128];
                nxt[8 + j] = tgn[(32 + quad * 8 + j) * 128];
            }
        }

        const s16x8 aq = qf[h];
#pragma unroll
        for (int nj = 0; nj < 4; ++nj) {
            s16x8 bk_ = zfrag;
            if (quad < 2)
                bk_ = *(const s16x8*)(B2 + swz128(nj * 16 + m, h * 16 + quad * 8));
            f32x4 s = __builtin_amdgcn_mfma_f32_16x16x32_bf16(
                aq, bk_, (f32x4){0.f, 0.f, 0.f, 0.f}, 0, 0, 0);
#pragma unroll
            for (int r = 0; r < 4; ++r) {
                const int row = r0 + quad * 4 + r;
                const float sval = s[r] * 0.25f;
                o0[h * 4096 + row * 64 + nj * 16 + m] = sval;
                myS[swz64(quad * 4 + r, nj * 16 + m)] = f2bf(sval);
            }
        }
        s16x8 bt0, bt1;
#pragma unroll
        for (int j = 0; j < 8; ++j) { bt0[j] = f2bf(cur[j]); bt1[j] = f2bf(cur[8 + j]); }

        f32x4 av = (f32x4){0.f, 0.f, 0.f, 0.f};
        f32x4 at = (f32x4){0.f, 0.f, 0.f, 0.f};
        {
            s16x8 sa0 = *(const s16x8*)(myS + swz64(m, quad * 8));
            s16x8 bv0 = *(const s16x8*)(B3 + swz64(h * 16 + m, quad * 8));
            av = __builtin_amdgcn_mfma_f32_16x16x32_bf16(sa0, bv0, av, 0, 0, 0);
            at = __builtin_amdgcn_mfma_f32_16x16x32_bf16(sa0, bt0, at, 0, 0, 0);
            s16x8 sa1 = *(const s16x8*)(myS + swz64(m, 32 + quad * 8));
            s16x8 bv1 = *(const s16x8*)(B3 + swz64(h * 16 + m, 32 + quad * 8));
            av = __builtin_amdgcn_mfma_f32_16x16x32_bf16(sa1, bv1, av, 0, 0, 0);
            at = __builtin_amdgcn_mfma_f32_16x16x32_bf16(sa1, bt1, at, 0, 0, 0);
        }
        // pack accumulators to bf16 now (they only ever get f2bf'd anyway)
        pv[h][0] = pack2(av[0], av[1]); pv[h][1] = pack2(av[2], av[3]);
        pt[h][0] = pack2(at[0], at[1]); pt[h][1] = pack2(at[2], at[3]);
    }
    __syncthreads();  // D: all cross-wave B2/B3 reads done before band reuse

    // ---------- tv -> B3 own band, ct -> B2 own band (wave-private) ---------
#pragma unroll
    for (int h = 0; h < 8; ++h) {
#pragma unroll
        for (int j = 0; j < 2; ++j) {
            const int ra = r0 + quad * 4 + 2 * j, rb = ra + 1;
            B3[swz128(ra, h * 16 + m)] = (short)(pv[h][j] & 0xffff);
            B3[swz128(rb, h * 16 + m)] = (short)(pv[h][j] >> 16);
            B2[swz128(ra, h * 16 + m)] = (short)(pt[h][j] & 0xffff);
            B2[swz128(rb, h * 16 + m)] = (short)(pt[h][j] >> 16);
        }
    }

    // ---------- output projections + LayerNorm ------------------------------
#pragma unroll
    for (int br = 0; br < 2; ++br) {
        const short* sA = br == 0 ? B3 : B2;
        const short* Wp = br == 0 ? Wot_t : Wtg_t;
        const float* bias = br == 0 ? bot : btg;
        const float* gam = br == 0 ? g_time : g_tgt;
        const float* bet = br == 0 ? b_time : b_tgt;
        float* outp = (br == 0 ? out1 : out2) + base;
        const float* resid = br == 0 ? XQ + base : nullptr;

        s16x8 a[4];
#pragma unroll
        for (int kk = 0; kk < 4; ++kk)
            a[kk] = *(const s16x8*)(sA + swz128(r0 + m, kk * 32 + quad * 8));
        f32x4 acc[8];
#pragma unroll
        for (int ni = 0; ni < 8; ++ni) {
            acc[ni] = (f32x4){0.f, 0.f, 0.f, 0.f};
#pragma unroll
            for (int kk = 0; kk < 4; ++kk)
                acc[ni] = __builtin_amdgcn_mfma_f32_16x16x32_bf16(
                    a[kk], wfrag(Wp, ni, kk, m, quad), acc[ni], 0, 0, 0);
        }
        float y[8][4];
        float s1[4] = {0.f, 0.f, 0.f, 0.f}, s2[4] = {0.f, 0.f, 0.f, 0.f};
#pragma unroll
        for (int ni = 0; ni < 8; ++ni) {
            const int col = ni * 16 + m;
            const float bb = bias[col];
#pragma unroll
            for (int r = 0; r < 4; ++r) {
                const int row = r0 + quad * 4 + r;
                float v = acc[ni][r] + bb;
                if (resid) v += resid[row * 128 + col];
                y[ni][r] = v;
                s1[r] += v;
                s2[r] += v * v;
            }
        }
#pragma unroll
        for (int mask = 1; mask < 16; mask <<= 1) {
#pragma unroll
            for (int r = 0; r < 4; ++r) {
                s1[r] += __shfl_xor(s1[r], mask, 64);
                s2[r] += __shfl_xor(s2[r], mask, 64);
            }
        }
        float mu[4], rstd[4];
#pragma unroll
        for (int r = 0; r < 4; ++r) {
            mu[r] = s1[r] * (1.0f / 128.0f);
            float var = s2[r] * (1.0f / 128.0f) - mu[r] * mu[r];
            rstd[r] = rsqrtf(var + 1e-5f);
        }
#pragma unroll
        for (int ni = 0; ni < 8; ++ni) {
            const int col = ni * 16 + m;
            const float g = gam[col], bb = bet[col];
#pragma unroll
            for (int r = 0; r < 4; ++r) {
                const int row = r0 + quad * 4 + r;
                outp[row * 128 + col] = (y[ni][r] - mu[r]) * rstd[r] * g + bb;
            }
        }
    }
}

extern "C" void kernel_launch(void* const* d_in, const int* in_sizes, int n_in,
                              void* d_out, int out_size, void* d_ws, size_t ws_size,
                              hipStream_t stream) {
    const float* XQ  = (const float*)d_in[0];
    const float* XK  = (const float*)d_in[1];
    const float* Tgt = (const float*)d_in[2];
    const float* Wq  = (const float*)d_in[3];
    const float* bq  = (const float*)d_in[4];
    const float* Wk  = (const float*)d_in[5];
    const float* bk  = (const float*)d_in[6];
    const float* Wv  = (const float*)d_in[7];
    const float* bv  = (const float*)d_in[8];
    const float* Wot = (const float*)d_in[9];
    const float* bot = (const float*)d_in[10];
    const float* Wtg = (const float*)d_in[11];
    const float* btg = (const float*)d_in[12];
    const float* g_time = (const float*)d_in[13];
    const float* b_time = (const float*)d_in[14];
    const float* g_tgt  = (const float*)d_in[15];
    const float* b_tgt  = (const float*)d_in[16];

    const int BN = in_sizes[0] / 8192;  // B*N

    short* Wt = (short*)d_ws;  // 5 * 128 * 128 bf16 = 160 KB

    float* out0 = (float*)d_out;
    float* out1 = out0 + (size_t)BN * 32768;
    float* out2 = out1 + (size_t)BN * 8192;

    k_prep<<<5, 256, 0, stream>>>(Wq, Wk, Wv, Wot, Wtg, Wt);
    k_main<<<BN, 256, 0, stream>>>(XQ, XK, Tgt, Wt, bq, bk, bv, bot, btg,
                                   g_time, b_time, g_tgt, b_tgt,
                                   out0, out1, out2);
}